// Round 2
// baseline (96.770 us; speedup 1.0000x reference)
//
#include <hip/hip_runtime.h>
#include <math.h>

#define NVIEW 3
#define HLOW 256
#define WLOW 256
#define NPIX (HLOW * WLOW)
#define NS 64
#define VOLN 128
#define IMGH 512
#define IMGW 512
#define BLK 256
#define SPLIT 4                       // waves per block, each takes NS/SPLIT samples
#define SEG_NS (NS / SPLIT)           // 16
#define RAYS_PER_BLOCK 64
#define BLOCKS_PER_VIEW (NPIX / RAYS_PER_BLOCK) // 1024

// Block = 64 consecutive rays x 4 depth segments (one segment per wave).
// Plain exp (no max-subtract: density is trilerp of N(0,1), |d| < ~6, no
// overflow risk in fp32); segments merge by simple addition in LDS.
__global__ __launch_bounds__(BLK) void raymarch_kernel(
    const float* __restrict__ intrs,    // [3,3,3]
    const float* __restrict__ c2ws,     // [3,4,4]
    const float* __restrict__ nearfars, // [3,2]
    const float* __restrict__ vol,      // [128,128,128] (D,H,W)
    float* __restrict__ depth_low,      // [3,256,256]
    float* __restrict__ partials)       // [3*1024][3]
{
    const int view   = blockIdx.x / BLOCKS_PER_VIEW;
    const int rayblk = blockIdx.x - view * BLOCKS_PER_VIEW;
    const int wave   = threadIdx.x >> 6;
    const int lane   = threadIdx.x & 63;
    const int ray    = rayblk * RAYS_PER_BLOCK + lane;
    const int row    = ray >> 8;
    const int col    = ray & 255;

    // pixel grid: linspace(0, 511, 256) along each dim
    const float px = 511.0f * (float)col * (1.0f / 255.0f);
    const float py = 511.0f * (float)row * (1.0f / 255.0f);

    // analytic 3x3 inverse of intr
    const float* K = intrs + view * 9;
    const float a = K[0], b = K[1], c = K[2];
    const float d = K[3], e = K[4], f = K[5];
    const float g = K[6], h = K[7], i9 = K[8];
    const float det = a * (e * i9 - f * h) - b * (d * i9 - f * g) + c * (d * h - e * g);
    const float id = 1.0f / det;
    const float m00 = (e * i9 - f * h) * id, m01 = -(b * i9 - c * h) * id, m02 = (b * f - c * e) * id;
    const float m10 = -(d * i9 - f * g) * id, m11 = (a * i9 - c * g) * id, m12 = -(a * f - c * d) * id;
    const float m20 = (d * h - e * g) * id, m21 = -(a * h - b * g) * id, m22 = (a * e - b * d) * id;

    const float cx = m00 * px + m01 * py + m02;
    const float cy = m10 * px + m11 * py + m12;
    const float cz = m20 * px + m21 * py + m22;
    const float inr = rsqrtf(cx * cx + cy * cy + cz * cz);
    const float ncx = cx * inr, ncy = cy * inr, ncz = cz * inr;

    const float* M = c2ws + view * 16;
    const float dx = M[0] * ncx + M[1] * ncy + M[2] * ncz;
    const float dy = M[4] * ncx + M[5] * ncy + M[6] * ncz;
    const float dz = M[8] * ncx + M[9] * ncy + M[10] * ncz;
    const float tx = M[3], ty = M[7], tz = M[11];

    const float nearv = nearfars[view * 2 + 0];
    const float farv  = nearfars[view * 2 + 1];
    const float zstep = (farv - nearv) * (1.0f / 63.0f);

    float lsum = 0.0f, zacc = 0.0f;
    float d6 = 0.0f, dout = 0.0f, cnt = 0.0f;
    const int s0 = wave * SEG_NS;

    #pragma unroll 4
    for (int i = 0; i < SEG_NS; ++i) {
        const float z = nearv + zstep * (float)(s0 + i);
        const float wxp = tx + dx * z;
        const float wyp = ty + dy * z;
        const float wzp = tz + dz * z;

        float gx = (wxp + 1.0f) * 0.5f * 127.0f;
        float gy = (wyp + 1.0f) * 0.5f * 127.0f;
        float gz = (wzp + 1.0f) * 0.5f * 127.0f;
        gx = fminf(fmaxf(gx, 0.0f), 127.0f);
        gy = fminf(fmaxf(gy, 0.0f), 127.0f);
        gz = fminf(fmaxf(gz, 0.0f), 127.0f);
        const float x0f = floorf(gx), y0f = floorf(gy), z0f = floorf(gz);
        const float fx = gx - x0f, fy = gy - y0f, fz = gz - z0f;
        const int x0 = (int)x0f, y0 = (int)y0f, z0 = (int)z0f;
        const int x1 = min(x0 + 1, VOLN - 1);
        const int y1 = min(y0 + 1, VOLN - 1);
        const int z1 = min(z0 + 1, VOLN - 1);

        const float* p0 = vol + z0 * (VOLN * VOLN);
        const float* p1 = vol + z1 * (VOLN * VOLN);
        const int ry0 = y0 * VOLN, ry1 = y1 * VOLN;
        const float c000 = p0[ry0 + x0], c001 = p0[ry0 + x1];
        const float c010 = p0[ry1 + x0], c011 = p0[ry1 + x1];
        const float c100 = p1[ry0 + x0], c101 = p1[ry0 + x1];
        const float c110 = p1[ry1 + x0], c111 = p1[ry1 + x1];

        const float c00 = c000 * (1.0f - fx) + c001 * fx;
        const float c01 = c010 * (1.0f - fx) + c011 * fx;
        const float c10 = c100 * (1.0f - fx) + c101 * fx;
        const float c11 = c110 * (1.0f - fx) + c111 * fx;
        const float c0 = c00 * (1.0f - fy) + c01 * fy;
        const float c1 = c10 * (1.0f - fy) + c11 * fy;
        const float dens = c0 * (1.0f - fz) + c1 * fz;

        const float w = __expf(dens);
        lsum += w;
        zacc += z * w;

        if (wave == 0 && i < 6) d6 += dens;           // wave-uniform branch
        const float r2 = wxp * wxp + wyp * wyp + wzp * wzp;
        if (r2 > 1.0f) { dout += dens; cnt += 1.0f; }
    }

    // cross-wave softmax-state merge (plain sums)
    __shared__ float sl[SPLIT][RAYS_PER_BLOCK];
    __shared__ float sz[SPLIT][RAYS_PER_BLOCK];
    sl[wave][lane] = lsum;
    sz[wave][lane] = zacc;

    // occ partial tree-reduction over all 256 threads
    __shared__ float o0[BLK], o1[BLK], o2[BLK];
    const int t = threadIdx.x;
    o0[t] = d6; o1[t] = dout; o2[t] = cnt;
    __syncthreads();

    if (t < RAYS_PER_BLOCK) {
        const float L = sl[0][t] + sl[1][t] + sl[2][t] + sl[3][t];
        const float Z = sz[0][t] + sz[1][t] + sz[2][t] + sz[3][t];
        // t == lane for wave 0, so ncz computed above is this ray's
        depth_low[view * NPIX + rayblk * RAYS_PER_BLOCK + t] = (Z / L) * ncz;
    }

    for (int off = BLK / 2; off > 0; off >>= 1) {
        if (t < off) {
            o0[t] += o0[t + off];
            o1[t] += o1[t + off];
            o2[t] += o2[t + off];
        }
        __syncthreads();
    }
    if (t == 0) {
        partials[blockIdx.x * 3 + 0] = o0[0];
        partials[blockIdx.x * 3 + 1] = o1[0];
        partials[blockIdx.x * 3 + 2] = o2[0];
    }
}

// One block per view: reduce the 1024 block-partials, write occ scalar.
__global__ __launch_bounds__(256) void reduce_occ_kernel(
    const float* __restrict__ partials, float* __restrict__ out_occ)
{
    const int view = blockIdx.x;
    const int t = threadIdx.x;
    __shared__ float s0[256], s1[256], s2[256];
    float a0 = 0.0f, a1 = 0.0f, a2 = 0.0f;
    for (int k = t; k < BLOCKS_PER_VIEW; k += 256) {
        const int bi = view * BLOCKS_PER_VIEW + k;
        a0 += partials[bi * 3 + 0];
        a1 += partials[bi * 3 + 1];
        a2 += partials[bi * 3 + 2];
    }
    s0[t] = a0; s1[t] = a1; s2[t] = a2;
    __syncthreads();
    for (int off = 128; off > 0; off >>= 1) {
        if (t < off) {
            s0[t] += s0[t + off];
            s1[t] += s1[t + off];
            s2[t] += s2[t + off];
        }
        __syncthreads();
    }
    if (t == 0) {
        out_occ[view] = s0[0] * (1.0f / (float)(NPIX * 6))
                      + s1[0] / (s2[0] + 1e-10f);
    }
}

// 256x256 -> 512x512 bilinear, jax.image.resize semantics:
// src = (i + 0.5) * 0.5 - 0.5; edge renormalization == index clamp.
__global__ __launch_bounds__(BLK) void upsample_kernel(
    const float* __restrict__ low, float* __restrict__ out)
{
    const int idx = blockIdx.x * BLK + threadIdx.x;
    const int view = idx / (IMGH * IMGW);
    const int rem = idx - view * (IMGH * IMGW);
    const int r = rem >> 9;
    const int cc = rem & 511;

    const float sy = (float)r * 0.5f - 0.25f;
    const float sx = (float)cc * 0.5f - 0.25f;
    const float y0f = floorf(sy), x0f = floorf(sx);
    const float wy = sy - y0f, wx = sx - x0f;
    const int y0 = (int)y0f, x0 = (int)x0f;
    const int y0c = max(y0, 0), y1c = min(y0 + 1, HLOW - 1);
    const int x0c = max(x0, 0), x1c = min(x0 + 1, WLOW - 1);

    const float* src = low + view * NPIX;
    const float v00 = src[y0c * WLOW + x0c];
    const float v01 = src[y0c * WLOW + x1c];
    const float v10 = src[y1c * WLOW + x0c];
    const float v11 = src[y1c * WLOW + x1c];

    const float top = v00 * (1.0f - wx) + v01 * wx;
    const float bot = v10 * (1.0f - wx) + v11 * wx;
    out[idx] = top * (1.0f - wy) + bot * wy;
}

extern "C" void kernel_launch(void* const* d_in, const int* in_sizes, int n_in,
                              void* d_out, int out_size, void* d_ws, size_t ws_size,
                              hipStream_t stream) {
    // input order: imgs, intrs, c2ws, near_fars, density_volume, stage_idx
    const float* intrs = (const float*)d_in[1];
    const float* c2ws  = (const float*)d_in[2];
    const float* nf    = (const float*)d_in[3];
    const float* vol   = (const float*)d_in[4];
    float* out = (float*)d_out;

    float* depth_low = (float*)d_ws;                    // 3*65536 floats
    float* partials  = depth_low + NVIEW * NPIX;        // 3*1024*3 floats

    raymarch_kernel<<<NVIEW * BLOCKS_PER_VIEW, BLK, 0, stream>>>(
        intrs, c2ws, nf, vol, depth_low, partials);
    reduce_occ_kernel<<<NVIEW, 256, 0, stream>>>(
        partials, out + NVIEW * IMGH * IMGW);
    upsample_kernel<<<(NVIEW * IMGH * IMGW) / BLK, BLK, 0, stream>>>(
        depth_low, out);
}

// Round 3
// 59.447 us; speedup vs baseline: 1.6278x; 1.6278x over previous
//
#include <hip/hip_runtime.h>
#include <math.h>

#define NVIEW 3
#define HLOW 256
#define WLOW 256
#define NPIX (HLOW * WLOW)
#define NS 64
#define VOLN 128
#define IMGH 512
#define IMGW 512
#define BLK 256
#define BLOCKS_PER_VIEW (NPIX / BLK) // 256

// One thread per (view, low-res pixel), 64 samples per thread, unroll 8 for
// memory-level parallelism (grid is 3 blocks/CU -> VGPRs are free).
// x-adjacent voxel pairs fetched as one float2 (dwordx2): 4 loads/sample.
// Plain exp softmax (density = trilerp of N(0,1), |d| small, no overflow).
__global__ __launch_bounds__(BLK) void raymarch_kernel(
    const float* __restrict__ intrs,    // [3,3,3]
    const float* __restrict__ c2ws,     // [3,4,4]
    const float* __restrict__ nearfars, // [3,2]
    const float* __restrict__ vol,      // [128,128,128] (D,H,W)
    float* __restrict__ depth_low,      // [3,256,256]
    float* __restrict__ partials)       // [3*256][3]
{
    const int view = blockIdx.x >> 8;
    const int pix  = ((blockIdx.x & 255) << 8) + threadIdx.x;
    const int row  = pix >> 8;
    const int col  = pix & 255;

    // pixel grid: linspace(0, 511, 256)
    const float px = 511.0f * (float)col * (1.0f / 255.0f);
    const float py = 511.0f * (float)row * (1.0f / 255.0f);

    // analytic 3x3 inverse of intr
    const float* K = intrs + view * 9;
    const float a = K[0], b = K[1], c = K[2];
    const float d = K[3], e = K[4], f = K[5];
    const float g = K[6], h = K[7], i9 = K[8];
    const float det = a * (e * i9 - f * h) - b * (d * i9 - f * g) + c * (d * h - e * g);
    const float id = 1.0f / det;
    const float m00 = (e * i9 - f * h) * id, m01 = -(b * i9 - c * h) * id, m02 = (b * f - c * e) * id;
    const float m10 = -(d * i9 - f * g) * id, m11 = (a * i9 - c * g) * id, m12 = -(a * f - c * d) * id;
    const float m20 = (d * h - e * g) * id, m21 = -(a * h - b * g) * id, m22 = (a * e - b * d) * id;

    const float cx = m00 * px + m01 * py + m02;
    const float cy = m10 * px + m11 * py + m12;
    const float cz = m20 * px + m21 * py + m22;
    const float inr = rsqrtf(cx * cx + cy * cy + cz * cz);
    const float ncx = cx * inr, ncy = cy * inr, ncz = cz * inr;

    const float* M = c2ws + view * 16;
    const float dx = M[0] * ncx + M[1] * ncy + M[2] * ncz;
    const float dy = M[4] * ncx + M[5] * ncy + M[6] * ncz;
    const float dz = M[8] * ncx + M[9] * ncy + M[10] * ncz;
    const float tx = M[3], ty = M[7], tz = M[11];

    const float nearv = nearfars[view * 2 + 0];
    const float farv  = nearfars[view * 2 + 1];
    const float zstep = (farv - nearv) * (1.0f / 63.0f);

    float lsum = 0.0f, zacc = 0.0f;
    float d6 = 0.0f, dout = 0.0f, cnt = 0.0f;

    #pragma unroll 8
    for (int s = 0; s < NS; ++s) {
        const float z = nearv + zstep * (float)s;
        const float wxp = tx + dx * z;
        const float wyp = ty + dy * z;
        const float wzp = tz + dz * z;

        float gx = (wxp + 1.0f) * 0.5f * 127.0f;
        float gy = (wyp + 1.0f) * 0.5f * 127.0f;
        float gz = (wzp + 1.0f) * 0.5f * 127.0f;
        gx = fminf(fmaxf(gx, 0.0f), 127.0f);
        gy = fminf(fmaxf(gy, 0.0f), 127.0f);
        gz = fminf(fmaxf(gz, 0.0f), 127.0f);
        const float x0f = floorf(gx), y0f = floorf(gy), z0f = floorf(gz);
        const float fx = gx - x0f, fy = gy - y0f, fz = gz - z0f;
        const int x0 = (int)x0f, y0 = (int)y0f, z0 = (int)z0f;
        const int y1 = min(y0 + 1, VOLN - 1);
        const int z1 = min(z0 + 1, VOLN - 1);
        // pair base: xb in [0,126]; c001 = pair.y always; c000 = pair[x0-xb]
        const int xb = min(x0, VOLN - 2);
        const int sel = x0 - xb; // 0 or 1

        const int b00 = (z0 * VOLN + y0) * VOLN + xb;
        const int b01 = (z0 * VOLN + y1) * VOLN + xb;
        const int b10 = (z1 * VOLN + y0) * VOLN + xb;
        const int b11 = (z1 * VOLN + y1) * VOLN + xb;
        const float2 v00 = *reinterpret_cast<const float2*>(vol + b00);
        const float2 v01 = *reinterpret_cast<const float2*>(vol + b01);
        const float2 v10 = *reinterpret_cast<const float2*>(vol + b10);
        const float2 v11 = *reinterpret_cast<const float2*>(vol + b11);

        const float c000 = sel ? v00.y : v00.x;
        const float c010 = sel ? v01.y : v01.x;
        const float c100 = sel ? v10.y : v10.x;
        const float c110 = sel ? v11.y : v11.x;

        const float c00 = c000 + (v00.y - c000) * fx;
        const float c01 = c010 + (v01.y - c010) * fx;
        const float c10 = c100 + (v10.y - c100) * fx;
        const float c11 = c110 + (v11.y - c110) * fx;
        const float c0 = c00 + (c01 - c00) * fy;
        const float c1 = c10 + (c11 - c10) * fy;
        const float dens = c0 + (c1 - c0) * fz;

        const float w = __expf(dens);
        lsum += w;
        zacc += z * w;

        if (s < 6) d6 += dens;
        const float r2 = wxp * wxp + wyp * wyp + wzp * wzp;
        if (r2 > 1.0f) { dout += dens; cnt += 1.0f; }
    }

    depth_low[view * NPIX + pix] = (zacc / lsum) * ncz;

    // deterministic block tree-reduction of the three occ partial sums
    __shared__ float s0[BLK], s1[BLK], s2[BLK];
    const int t = threadIdx.x;
    s0[t] = d6; s1[t] = dout; s2[t] = cnt;
    __syncthreads();
    for (int off = BLK / 2; off > 0; off >>= 1) {
        if (t < off) {
            s0[t] += s0[t + off];
            s1[t] += s1[t + off];
            s2[t] += s2[t + off];
        }
        __syncthreads();
    }
    if (t == 0) {
        partials[blockIdx.x * 3 + 0] = s0[0];
        partials[blockIdx.x * 3 + 1] = s1[0];
        partials[blockIdx.x * 3 + 2] = s2[0];
    }
}

// One block per view: reduce the 256 block-partials, write occ scalar.
__global__ __launch_bounds__(BLOCKS_PER_VIEW) void reduce_occ_kernel(
    const float* __restrict__ partials, float* __restrict__ out_occ)
{
    const int view = blockIdx.x;
    const int t = threadIdx.x;
    __shared__ float s0[BLOCKS_PER_VIEW], s1[BLOCKS_PER_VIEW], s2[BLOCKS_PER_VIEW];
    const int bi = view * BLOCKS_PER_VIEW + t;
    s0[t] = partials[bi * 3 + 0];
    s1[t] = partials[bi * 3 + 1];
    s2[t] = partials[bi * 3 + 2];
    __syncthreads();
    for (int off = BLOCKS_PER_VIEW / 2; off > 0; off >>= 1) {
        if (t < off) {
            s0[t] += s0[t + off];
            s1[t] += s1[t + off];
            s2[t] += s2[t + off];
        }
        __syncthreads();
    }
    if (t == 0) {
        out_occ[view] = s0[0] * (1.0f / (float)(NPIX * 6))
                      + s1[0] / (s2[0] + 1e-10f);
    }
}

// 256x256 -> 512x512 bilinear, jax.image.resize semantics:
// src = (i + 0.5) * 0.5 - 0.5; edge renormalization == index clamp.
__global__ __launch_bounds__(BLK) void upsample_kernel(
    const float* __restrict__ low, float* __restrict__ out)
{
    const int idx = blockIdx.x * BLK + threadIdx.x;
    const int view = idx / (IMGH * IMGW);
    const int rem = idx - view * (IMGH * IMGW);
    const int r = rem >> 9;
    const int cc = rem & 511;

    const float sy = (float)r * 0.5f - 0.25f;
    const float sx = (float)cc * 0.5f - 0.25f;
    const float y0f = floorf(sy), x0f = floorf(sx);
    const float wy = sy - y0f, wx = sx - x0f;
    const int y0 = (int)y0f, x0 = (int)x0f;
    const int y0c = max(y0, 0), y1c = min(y0 + 1, HLOW - 1);
    const int x0c = max(x0, 0), x1c = min(x0 + 1, WLOW - 1);

    const float* src = low + view * NPIX;
    const float v00 = src[y0c * WLOW + x0c];
    const float v01 = src[y0c * WLOW + x1c];
    const float v10 = src[y1c * WLOW + x0c];
    const float v11 = src[y1c * WLOW + x1c];

    const float top = v00 * (1.0f - wx) + v01 * wx;
    const float bot = v10 * (1.0f - wx) + v11 * wx;
    out[idx] = top * (1.0f - wy) + bot * wy;
}

extern "C" void kernel_launch(void* const* d_in, const int* in_sizes, int n_in,
                              void* d_out, int out_size, void* d_ws, size_t ws_size,
                              hipStream_t stream) {
    // input order: imgs, intrs, c2ws, near_fars, density_volume, stage_idx
    const float* intrs = (const float*)d_in[1];
    const float* c2ws  = (const float*)d_in[2];
    const float* nf    = (const float*)d_in[3];
    const float* vol   = (const float*)d_in[4];
    float* out = (float*)d_out;

    float* depth_low = (float*)d_ws;                    // 3*65536 floats
    float* partials  = depth_low + NVIEW * NPIX;        // 3*256*3 floats

    raymarch_kernel<<<NVIEW * BLOCKS_PER_VIEW, BLK, 0, stream>>>(
        intrs, c2ws, nf, vol, depth_low, partials);
    reduce_occ_kernel<<<NVIEW, BLOCKS_PER_VIEW, 0, stream>>>(
        partials, out + NVIEW * IMGH * IMGW);
    upsample_kernel<<<(NVIEW * IMGH * IMGW) / BLK, BLK, 0, stream>>>(
        depth_low, out);
}